// Round 9
// baseline (979.444 us; speedup 1.0000x reference)
//
#include <hip/hip_runtime.h>
#include <hip/hip_bf16.h>

// GraphSAGE 2-layer, N=50000, d=128->32->32, E=800000, fp32.
//
// R8 post-mortem: per-kernel work sums to ~105us but measured 192us; a
// ~12us/kernel-boundary overhead model reproduces R4/R5/R6/R8 totals. The
// bottleneck is 8 small dispatches, not any kernel. R9: ONE persistent
// kernel (512 blocks x 256 thr, capacity>=4 blocks/CU vs 2 needed -> all
// co-resident, no deadlock) with device-scope grid barriers (release RMW
// arrive + acquire poll, fresh counter/phase, memset'd before launch).
// Fine sort eliminated: aggregation runs per 64-dst bucket straight from
// ebuf into an LDS f32 accumulator (ds_add_f32, conflict-free banks).
// Phases: bcount | rowscan | (totals-scan || kproj128) | bscatter | agg1 |
//         kproj32 | agg2.   bf16 zn + fp32 zs retained (R6/R8-proven).

#define N_NODES 50000
#define NBUK 782  // 64-dst buckets = ceil(50000/64)
#define NT 782    // 64-node kproj tiles
#define G 512     // persistent grid

__device__ __forceinline__ unsigned short f2bf(float f) {  // RNE
  unsigned int u = __float_as_uint(f);
  return (unsigned short)((u + 0x7fffu + ((u >> 16) & 1u)) >> 16);
}
__device__ __forceinline__ float bf2f(unsigned short v) {
  return __uint_as_float(((unsigned int)v) << 16);
}

__device__ __forceinline__ void gbar(int* __restrict__ bar, int idx) {
  __syncthreads();
  if (threadIdx.x == 0) {
    __hip_atomic_fetch_add(&bar[idx], 1, __ATOMIC_RELEASE,
                           __HIP_MEMORY_SCOPE_AGENT);
    while (__hip_atomic_load(&bar[idx], __ATOMIC_ACQUIRE,
                             __HIP_MEMORY_SCOPE_AGENT) < G)
      __builtin_amdgcn_s_sleep(8);
  }
  __syncthreads();
}

// 64-node x 64-col projection tile, K-chunked by 32. smem: xs[64*36]+ws[32*64]
__device__ void kproj_tile(const float* __restrict__ in,
                           const float* __restrict__ Wl,
                           const float* __restrict__ Wr,
                           unsigned short* __restrict__ zn,
                           float* __restrict__ zs, int N, int K, int tile,
                           float* smem) {
  float* xs = smem;            // 64*36
  float* ws = smem + 64 * 36;  // 32*64
  const int t = threadIdx.x;
  const int n0 = tile * 64;
  int nvalid = N - n0;
  if (nvalid > 64) nvalid = 64;
  const int tx = t & 15, ty = t >> 4;
  const int c0 = tx * 4, nl = ty * 4;
  float acc[4][4];
#pragma unroll
  for (int i = 0; i < 4; i++)
#pragma unroll
    for (int j = 0; j < 4; j++) acc[i][j] = 0.f;

  for (int kc = 0; kc < K; kc += 32) {
    for (int i = t; i < 32 * 32; i += 256) {
      int k = i >> 5, c = i & 31;
      ws[k * 64 + c] = Wl[(size_t)(kc + k) * 32 + c];
      ws[k * 64 + 32 + c] = Wr[(size_t)(kc + k) * 32 + c];
    }
    for (int i = t; i < nvalid * 8; i += 256) {
      int n = i >> 3, q = i & 7;
      float4 v = *(const float4*)(in + (size_t)(n0 + n) * K + kc + q * 4);
      *(float4*)(xs + n * 36 + q * 4) = v;
    }
    __syncthreads();
    const float* x0 = xs + (nl + 0) * 36;
    const float* x1 = xs + (nl + 1) * 36;
    const float* x2 = xs + (nl + 2) * 36;
    const float* x3 = xs + (nl + 3) * 36;
    for (int k = 0; k < 32; k += 4) {
      float4 xa = *(const float4*)(x0 + k);
      float4 xb = *(const float4*)(x1 + k);
      float4 xc = *(const float4*)(x2 + k);
      float4 xd = *(const float4*)(x3 + k);
#pragma unroll
      for (int kk = 0; kk < 4; kk++) {
        float4 w = *(const float4*)(ws + (k + kk) * 64 + c0);
        float va = ((const float*)&xa)[kk];
        float vb = ((const float*)&xb)[kk];
        float vc = ((const float*)&xc)[kk];
        float vd = ((const float*)&xd)[kk];
        acc[0][0] += va * w.x; acc[0][1] += va * w.y;
        acc[0][2] += va * w.z; acc[0][3] += va * w.w;
        acc[1][0] += vb * w.x; acc[1][1] += vb * w.y;
        acc[1][2] += vb * w.z; acc[1][3] += vb * w.w;
        acc[2][0] += vc * w.x; acc[2][1] += vc * w.y;
        acc[2][2] += vc * w.z; acc[2][3] += vc * w.w;
        acc[3][0] += vd * w.x; acc[3][1] += vd * w.y;
        acc[3][2] += vd * w.z; acc[3][3] += vd * w.w;
      }
    }
    __syncthreads();
  }
#pragma unroll
  for (int i = 0; i < 4; i++) {
    int node = n0 + nl + i;
    if (node < N) {
      if (tx < 8) {
        ushort4 p;
        p.x = f2bf(acc[i][0]); p.y = f2bf(acc[i][1]);
        p.z = f2bf(acc[i][2]); p.w = f2bf(acc[i][3]);
        *(ushort4*)(zn + (size_t)node * 32 + c0) = p;
      } else {
        *(float4*)(zs + (size_t)node * 32 + (c0 - 32)) =
            make_float4(acc[i][0], acc[i][1], acc[i][2], acc[i][3]);
      }
    }
  }
}

// per-bucket aggregation from ebuf: LDS f32 accumulate, then epilogue.
__device__ void agg_bucket(const unsigned short* __restrict__ zn,
                           const float* __restrict__ zs,
                           const float* __restrict__ bias,
                           float* __restrict__ outp, int N, int k, int relu,
                           const int* __restrict__ bb,
                           const int* __restrict__ ebuf, float* smem) {
  float* acc = smem;                  // 64*32
  int* scnt = (int*)(smem + 2048);    // 64
  const int t = threadIdx.x;
  for (int i = t; i < 2048; i += 256) acc[i] = 0.f;
  if (t < 64) scnt[t] = 0;
  __syncthreads();
  const int r0 = bb[k], r1 = bb[k + 1];
  const int hw = t >> 5, j = t & 31;
  int e = r0 + hw;
  for (; e + 8 < r1; e += 16) {  // 2 gathers in flight per half-wave stream
    int v0 = ebuf[e], v1 = ebuf[e + 8];
    float g0 = bf2f(zn[(size_t)(v0 >> 6) * 32 + j]);
    float g1 = bf2f(zn[(size_t)(v1 >> 6) * 32 + j]);
    atomicAdd(&acc[(v0 & 63) * 32 + j], g0);
    atomicAdd(&acc[(v1 & 63) * 32 + j], g1);
    if (j == 0) {
      atomicAdd(&scnt[v0 & 63], 1);
      atomicAdd(&scnt[v1 & 63], 1);
    }
  }
  for (; e < r1; e += 8) {
    int v0 = ebuf[e];
    float g0 = bf2f(zn[(size_t)(v0 >> 6) * 32 + j]);
    atomicAdd(&acc[(v0 & 63) * 32 + j], g0);
    if (j == 0) atomicAdd(&scnt[v0 & 63], 1);
  }
  __syncthreads();
  for (int i = t; i < 2048; i += 256) {
    int dl = i >> 5, jj = i & 31;
    int node = (k << 6) + dl;
    if (node < N) {
      int c = scnt[dl];
      float m = acc[i] / (float)(c > 1 ? c : 1);
      float v = m + bias[jj] + zs[(size_t)node * 32 + jj];
      if (relu) v = fmaxf(v, 0.f);
      outp[(size_t)node * 32 + jj] = v;
    }
  }
  __syncthreads();
}

__global__ __launch_bounds__(256, 4) void k_all(
    const float* __restrict__ x, const int* __restrict__ src,
    const int* __restrict__ dst, const float* __restrict__ W1l,
    const float* __restrict__ b1, const float* __restrict__ W1r,
    const float* __restrict__ W2l, const float* __restrict__ b2,
    const float* __restrict__ W2r, float* __restrict__ out,
    float* __restrict__ zs1, float* __restrict__ zs2,
    float* __restrict__ hbuf, unsigned short* __restrict__ zn1,
    unsigned short* __restrict__ zn2, int* __restrict__ ebuf,
    int* __restrict__ blkhist, int* __restrict__ bb,
    int* __restrict__ totals, int* __restrict__ bar, int N, int E,
    int chunk) {
  __shared__ float smem[4352];  // 17408 B: max(kproj 4352f, agg 2112f, hist)
  int* ismem = (int*)smem;
  const int t = threadIdx.x, b = blockIdx.x;

  // ---- Ph0: per-block bucket histogram -----------------------------------
  for (int i = t; i < NBUK; i += 256) ismem[i] = 0;
  __syncthreads();
  const int e0 = b * chunk;
  int e1 = e0 + chunk;
  if (e1 > E) e1 = E;
  for (int e = e0 + t; e < e1; e += 256) atomicAdd(&ismem[dst[e] >> 6], 1);
  __syncthreads();
  for (int i = t; i < NBUK; i += 256) blkhist[(size_t)i * G + b] = ismem[i];
  gbar(bar, 0);

  // ---- Ph1: per-bucket row scans (offsets within bucket) -----------------
  for (int r = b; r < NBUK; r += G) {
    int* row = blkhist + (size_t)r * G;
    int2 v = *(int2*)(row + t * 2);
    int s = v.x + v.y;
    ismem[t] = s;
    __syncthreads();
    for (int off = 1; off < 256; off <<= 1) {
      int tmp = (t >= off) ? ismem[t - off] : 0;
      __syncthreads();
      ismem[t] += tmp;
      __syncthreads();
    }
    int excl = ismem[t] - s;
    int2 o;
    o.x = excl;
    o.y = excl + v.x;
    *(int2*)(row + t * 2) = o;
    if (t == 255) totals[r] = ismem[255];
    __syncthreads();
  }
  gbar(bar, 1);

  // ---- Ph2: block0 scans bucket totals -> bb; others run kproj(K=128) ----
  if (b == 0) {
    int v[4];
    int ssum = 0;
#pragma unroll
    for (int q = 0; q < 4; q++) {
      int idx = t * 4 + q;
      v[q] = (idx < NBUK) ? totals[idx] : 0;
      ssum += v[q];
    }
    ismem[t] = ssum;
    __syncthreads();
    for (int off = 1; off < 256; off <<= 1) {
      int tmp = (t >= off) ? ismem[t - off] : 0;
      __syncthreads();
      ismem[t] += tmp;
      __syncthreads();
    }
    int base = ismem[t] - ssum;
#pragma unroll
    for (int q = 0; q < 4; q++) {
      int idx = t * 4 + q;
      if (idx < NBUK) {
        bb[idx] = base;
        base += v[q];
      }
    }
    if (t == 0) bb[NBUK] = E;
  } else {
    for (int tile = b - 1; tile < NT; tile += (G - 1))
      kproj_tile(x, W1l, W1r, zn1, zs1, N, 128, tile, smem);
  }
  gbar(bar, 2);

  // ---- Ph3: scatter edges into bucket-grouped ebuf -----------------------
  for (int i = t; i < NBUK; i += 256)
    ismem[i] = bb[i] + blkhist[(size_t)i * G + b];
  __syncthreads();
  for (int e = e0 + t; e < e1; e += 256) {
    int d = dst[e], s = src[e];
    int pos = atomicAdd(&ismem[d >> 6], 1);
    ebuf[pos] = (s << 6) | (d & 63);
  }
  gbar(bar, 3);

  // ---- Ph4: layer-1 aggregation -> hbuf (relu) ---------------------------
  for (int k = b; k < NBUK; k += G)
    agg_bucket(zn1, zs1, b1, hbuf, N, k, 1, bb, ebuf, smem);
  gbar(bar, 4);

  // ---- Ph5: kproj(K=32) on hbuf -> zn2, zs2 ------------------------------
  for (int tile = b; tile < NT; tile += G)
    kproj_tile(hbuf, W2l, W2r, zn2, zs2, N, 32, tile, smem);
  gbar(bar, 5);

  // ---- Ph6: layer-2 aggregation -> out -----------------------------------
  for (int k = b; k < NBUK; k += G)
    agg_bucket(zn2, zs2, b2, out, N, k, 0, bb, ebuf, smem);
}

extern "C" void kernel_launch(void* const* d_in, const int* in_sizes, int n_in,
                              void* d_out, int out_size, void* d_ws,
                              size_t ws_size, hipStream_t stream) {
  const float* x = (const float*)d_in[0];
  const int* ei = (const int*)d_in[1];  // int32 (harness narrows int64)
  const float* W1l = (const float*)d_in[2];
  const float* b1 = (const float*)d_in[3];
  const float* W1r = (const float*)d_in[4];
  const float* W2l = (const float*)d_in[5];
  const float* b2 = (const float*)d_in[6];
  const float* W2r = (const float*)d_in[7];
  float* out = (float*)d_out;

  const int N = N_NODES;
  const int E = in_sizes[1] / 2;  // 800000
  const int chunk = (E + G - 1) / G;

  float* zs1 = (float*)d_ws;                     // N*32 f32
  float* zs2 = zs1 + (size_t)N * 32;             // N*32 f32
  float* hbuf = zs2 + (size_t)N * 32;            // N*32 f32
  unsigned short* zn1 = (unsigned short*)(hbuf + (size_t)N * 32);  // N*32
  unsigned short* zn2 = zn1 + (size_t)N * 32;    // N*32 bf16
  int* ebuf = (int*)(zn2 + (size_t)N * 32);      // E
  int* blkhist = ebuf + E;                       // NBUK*G
  int* bb = blkhist + (size_t)NBUK * G;          // NBUK+1
  int* totals = bb + NBUK + 1;                   // NBUK
  int* bar = (int*)(((size_t)(totals + NBUK) + 63) & ~(size_t)63);  // 16 ints

  hipMemsetAsync(bar, 0, 64, stream);

  const int* srcp = ei;
  const int* dstp = ei + E;

  k_all<<<G, 256, 0, stream>>>(x, srcp, dstp, W1l, b1, W1r, W2l, b2, W2r, out,
                               zs1, zs2, hbuf, zn1, zn2, ebuf, blkhist, bb,
                               totals, bar, N, E, chunk);
}

// Round 10
// 755.394 us; speedup vs baseline: 1.2966x; 1.2966x over previous
//
#include <hip/hip_runtime.h>
#include <hip/hip_bf16.h>

// GraphSAGE 2-layer, N=50000, d=128->32->32, E=800000, fp32.
//
// R9 post-mortem: persistent kernel ran 938us at 3% VALUBusy / 2% HBM -- the
// grid-barrier spin polled with agent-scope ACQUIRE loads, and on gfx950
// every agent acquire emits buffer_inv sc1 = full per-XCD L2 invalidate.
// ~500 spinning blocks continuously nuked all 8 L2s while stragglers worked;
// the L3-resident working set kept FETCH_SIZE low while latency exploded.
// R10: poll RELAXED (no invalidation), single ACQUIRE load after the
// condition holds (one wbl2 on release + one inv on exit per block/barrier).
// Also: agg gather ILP 2->4 per half-wave stream (fixed 8 waves/CU makes
// in-flight loads the only latency lever).
//
// Phases: bcount | rowscan | (totals-scan || kproj128) | bscatter | agg1 |
//         kproj32 | agg2.   bf16 zn + fp32 zs retained (R6/R8-proven).

#define N_NODES 50000
#define NBUK 782  // 64-dst buckets = ceil(50000/64)
#define NT 782    // 64-node kproj tiles
#define G 512     // persistent grid (2 blocks/CU of 4-block capacity)

__device__ __forceinline__ unsigned short f2bf(float f) {  // RNE
  unsigned int u = __float_as_uint(f);
  return (unsigned short)((u + 0x7fffu + ((u >> 16) & 1u)) >> 16);
}
__device__ __forceinline__ float bf2f(unsigned short v) {
  return __uint_as_float(((unsigned int)v) << 16);
}

__device__ __forceinline__ void gbar(int* __restrict__ bar, int idx) {
  __syncthreads();
  if (threadIdx.x == 0) {
    __hip_atomic_fetch_add(&bar[idx], 1, __ATOMIC_RELEASE,
                           __HIP_MEMORY_SCOPE_AGENT);
    // RELAXED poll: coherent read, no L2 invalidate per iteration.
    while (__hip_atomic_load(&bar[idx], __ATOMIC_RELAXED,
                             __HIP_MEMORY_SCOPE_AGENT) < G)
      __builtin_amdgcn_s_sleep(8);
    // Single acquire to order subsequent reads (one buffer_inv, not 1000s).
    (void)__hip_atomic_load(&bar[idx], __ATOMIC_ACQUIRE,
                            __HIP_MEMORY_SCOPE_AGENT);
  }
  __syncthreads();
}

// 64-node x 64-col projection tile, K-chunked by 32. smem: xs[64*36]+ws[32*64]
__device__ void kproj_tile(const float* __restrict__ in,
                           const float* __restrict__ Wl,
                           const float* __restrict__ Wr,
                           unsigned short* __restrict__ zn,
                           float* __restrict__ zs, int N, int K, int tile,
                           float* smem) {
  float* xs = smem;            // 64*36
  float* ws = smem + 64 * 36;  // 32*64
  const int t = threadIdx.x;
  const int n0 = tile * 64;
  int nvalid = N - n0;
  if (nvalid > 64) nvalid = 64;
  const int tx = t & 15, ty = t >> 4;
  const int c0 = tx * 4, nl = ty * 4;
  float acc[4][4];
#pragma unroll
  for (int i = 0; i < 4; i++)
#pragma unroll
    for (int j = 0; j < 4; j++) acc[i][j] = 0.f;

  for (int kc = 0; kc < K; kc += 32) {
    for (int i = t; i < 32 * 32; i += 256) {
      int k = i >> 5, c = i & 31;
      ws[k * 64 + c] = Wl[(size_t)(kc + k) * 32 + c];
      ws[k * 64 + 32 + c] = Wr[(size_t)(kc + k) * 32 + c];
    }
    for (int i = t; i < nvalid * 8; i += 256) {
      int n = i >> 3, q = i & 7;
      float4 v = *(const float4*)(in + (size_t)(n0 + n) * K + kc + q * 4);
      *(float4*)(xs + n * 36 + q * 4) = v;
    }
    __syncthreads();
    const float* x0 = xs + (nl + 0) * 36;
    const float* x1 = xs + (nl + 1) * 36;
    const float* x2 = xs + (nl + 2) * 36;
    const float* x3 = xs + (nl + 3) * 36;
    for (int k = 0; k < 32; k += 4) {
      float4 xa = *(const float4*)(x0 + k);
      float4 xb = *(const float4*)(x1 + k);
      float4 xc = *(const float4*)(x2 + k);
      float4 xd = *(const float4*)(x3 + k);
#pragma unroll
      for (int kk = 0; kk < 4; kk++) {
        float4 w = *(const float4*)(ws + (k + kk) * 64 + c0);
        float va = ((const float*)&xa)[kk];
        float vb = ((const float*)&xb)[kk];
        float vc = ((const float*)&xc)[kk];
        float vd = ((const float*)&xd)[kk];
        acc[0][0] += va * w.x; acc[0][1] += va * w.y;
        acc[0][2] += va * w.z; acc[0][3] += va * w.w;
        acc[1][0] += vb * w.x; acc[1][1] += vb * w.y;
        acc[1][2] += vb * w.z; acc[1][3] += vb * w.w;
        acc[2][0] += vc * w.x; acc[2][1] += vc * w.y;
        acc[2][2] += vc * w.z; acc[2][3] += vc * w.w;
        acc[3][0] += vd * w.x; acc[3][1] += vd * w.y;
        acc[3][2] += vd * w.z; acc[3][3] += vd * w.w;
      }
    }
    __syncthreads();
  }
#pragma unroll
  for (int i = 0; i < 4; i++) {
    int node = n0 + nl + i;
    if (node < N) {
      if (tx < 8) {
        ushort4 p;
        p.x = f2bf(acc[i][0]); p.y = f2bf(acc[i][1]);
        p.z = f2bf(acc[i][2]); p.w = f2bf(acc[i][3]);
        *(ushort4*)(zn + (size_t)node * 32 + c0) = p;
      } else {
        *(float4*)(zs + (size_t)node * 32 + (c0 - 32)) =
            make_float4(acc[i][0], acc[i][1], acc[i][2], acc[i][3]);
      }
    }
  }
}

// per-bucket aggregation from ebuf: LDS f32 accumulate, then epilogue.
// 8 half-wave streams cover residues e==hw (mod 8); 4 gathers in flight each.
__device__ void agg_bucket(const unsigned short* __restrict__ zn,
                           const float* __restrict__ zs,
                           const float* __restrict__ bias,
                           float* __restrict__ outp, int N, int k, int relu,
                           const int* __restrict__ bb,
                           const int* __restrict__ ebuf, float* smem) {
  float* acc = smem;                  // 64*32
  int* scnt = (int*)(smem + 2048);    // 64
  const int t = threadIdx.x;
  for (int i = t; i < 2048; i += 256) acc[i] = 0.f;
  if (t < 64) scnt[t] = 0;
  __syncthreads();
  const int r0 = bb[k], r1 = bb[k + 1];
  const int hw = t >> 5, j = t & 31;
  int e = r0 + hw;
  for (; e + 24 < r1; e += 32) {  // 4 gathers in flight per stream
    int v0 = ebuf[e], v1 = ebuf[e + 8], v2 = ebuf[e + 16], v3 = ebuf[e + 24];
    float g0 = bf2f(zn[(size_t)(v0 >> 6) * 32 + j]);
    float g1 = bf2f(zn[(size_t)(v1 >> 6) * 32 + j]);
    float g2 = bf2f(zn[(size_t)(v2 >> 6) * 32 + j]);
    float g3 = bf2f(zn[(size_t)(v3 >> 6) * 32 + j]);
    atomicAdd(&acc[(v0 & 63) * 32 + j], g0);
    atomicAdd(&acc[(v1 & 63) * 32 + j], g1);
    atomicAdd(&acc[(v2 & 63) * 32 + j], g2);
    atomicAdd(&acc[(v3 & 63) * 32 + j], g3);
    if (j == 0) {
      atomicAdd(&scnt[v0 & 63], 1);
      atomicAdd(&scnt[v1 & 63], 1);
      atomicAdd(&scnt[v2 & 63], 1);
      atomicAdd(&scnt[v3 & 63], 1);
    }
  }
  for (; e < r1; e += 8) {
    int v0 = ebuf[e];
    float g0 = bf2f(zn[(size_t)(v0 >> 6) * 32 + j]);
    atomicAdd(&acc[(v0 & 63) * 32 + j], g0);
    if (j == 0) atomicAdd(&scnt[v0 & 63], 1);
  }
  __syncthreads();
  for (int i = t; i < 2048; i += 256) {
    int dl = i >> 5, jj = i & 31;
    int node = (k << 6) + dl;
    if (node < N) {
      int c = scnt[dl];
      float m = acc[i] / (float)(c > 1 ? c : 1);
      float v = m + bias[jj] + zs[(size_t)node * 32 + jj];
      if (relu) v = fmaxf(v, 0.f);
      outp[(size_t)node * 32 + jj] = v;
    }
  }
  __syncthreads();
}

__global__ __launch_bounds__(256, 4) void k_all(
    const float* __restrict__ x, const int* __restrict__ src,
    const int* __restrict__ dst, const float* __restrict__ W1l,
    const float* __restrict__ b1, const float* __restrict__ W1r,
    const float* __restrict__ W2l, const float* __restrict__ b2,
    const float* __restrict__ W2r, float* __restrict__ out,
    float* __restrict__ zs1, float* __restrict__ zs2,
    float* __restrict__ hbuf, unsigned short* __restrict__ zn1,
    unsigned short* __restrict__ zn2, int* __restrict__ ebuf,
    int* __restrict__ blkhist, int* __restrict__ bb,
    int* __restrict__ totals, int* __restrict__ bar, int N, int E,
    int chunk) {
  __shared__ float smem[4352];  // 17408 B
  int* ismem = (int*)smem;
  const int t = threadIdx.x, b = blockIdx.x;

  // ---- Ph0: per-block bucket histogram -----------------------------------
  for (int i = t; i < NBUK; i += 256) ismem[i] = 0;
  __syncthreads();
  const int e0 = b * chunk;
  int e1 = e0 + chunk;
  if (e1 > E) e1 = E;
  for (int e = e0 + t; e < e1; e += 256) atomicAdd(&ismem[dst[e] >> 6], 1);
  __syncthreads();
  for (int i = t; i < NBUK; i += 256) blkhist[(size_t)i * G + b] = ismem[i];
  gbar(bar, 0);

  // ---- Ph1: per-bucket row scans (offsets within bucket) -----------------
  for (int r = b; r < NBUK; r += G) {
    int* row = blkhist + (size_t)r * G;
    int2 v = *(int2*)(row + t * 2);
    int s = v.x + v.y;
    ismem[t] = s;
    __syncthreads();
    for (int off = 1; off < 256; off <<= 1) {
      int tmp = (t >= off) ? ismem[t - off] : 0;
      __syncthreads();
      ismem[t] += tmp;
      __syncthreads();
    }
    int excl = ismem[t] - s;
    int2 o;
    o.x = excl;
    o.y = excl + v.x;
    *(int2*)(row + t * 2) = o;
    if (t == 255) totals[r] = ismem[255];
    __syncthreads();
  }
  gbar(bar, 1);

  // ---- Ph2: block0 scans bucket totals -> bb; others run kproj(K=128) ----
  if (b == 0) {
    int v[4];
    int ssum = 0;
#pragma unroll
    for (int q = 0; q < 4; q++) {
      int idx = t * 4 + q;
      v[q] = (idx < NBUK) ? totals[idx] : 0;
      ssum += v[q];
    }
    ismem[t] = ssum;
    __syncthreads();
    for (int off = 1; off < 256; off <<= 1) {
      int tmp = (t >= off) ? ismem[t - off] : 0;
      __syncthreads();
      ismem[t] += tmp;
      __syncthreads();
    }
    int base = ismem[t] - ssum;
#pragma unroll
    for (int q = 0; q < 4; q++) {
      int idx = t * 4 + q;
      if (idx < NBUK) {
        bb[idx] = base;
        base += v[q];
      }
    }
    if (t == 0) bb[NBUK] = E;
  } else {
    for (int tile = b - 1; tile < NT; tile += (G - 1))
      kproj_tile(x, W1l, W1r, zn1, zs1, N, 128, tile, smem);
  }
  gbar(bar, 2);

  // ---- Ph3: scatter edges into bucket-grouped ebuf -----------------------
  for (int i = t; i < NBUK; i += 256)
    ismem[i] = bb[i] + blkhist[(size_t)i * G + b];
  __syncthreads();
  for (int e = e0 + t; e < e1; e += 256) {
    int d = dst[e], s = src[e];
    int pos = atomicAdd(&ismem[d >> 6], 1);
    ebuf[pos] = (s << 6) | (d & 63);
  }
  gbar(bar, 3);

  // ---- Ph4: layer-1 aggregation -> hbuf (relu) ---------------------------
  for (int k = b; k < NBUK; k += G)
    agg_bucket(zn1, zs1, b1, hbuf, N, k, 1, bb, ebuf, smem);
  gbar(bar, 4);

  // ---- Ph5: kproj(K=32) on hbuf -> zn2, zs2 ------------------------------
  for (int tile = b; tile < NT; tile += G)
    kproj_tile(hbuf, W2l, W2r, zn2, zs2, N, 32, tile, smem);
  gbar(bar, 5);

  // ---- Ph6: layer-2 aggregation -> out -----------------------------------
  for (int k = b; k < NBUK; k += G)
    agg_bucket(zn2, zs2, b2, out, N, k, 0, bb, ebuf, smem);
}

extern "C" void kernel_launch(void* const* d_in, const int* in_sizes, int n_in,
                              void* d_out, int out_size, void* d_ws,
                              size_t ws_size, hipStream_t stream) {
  const float* x = (const float*)d_in[0];
  const int* ei = (const int*)d_in[1];  // int32 (harness narrows int64)
  const float* W1l = (const float*)d_in[2];
  const float* b1 = (const float*)d_in[3];
  const float* W1r = (const float*)d_in[4];
  const float* W2l = (const float*)d_in[5];
  const float* b2 = (const float*)d_in[6];
  const float* W2r = (const float*)d_in[7];
  float* out = (float*)d_out;

  const int N = N_NODES;
  const int E = in_sizes[1] / 2;  // 800000
  const int chunk = (E + G - 1) / G;

  float* zs1 = (float*)d_ws;                     // N*32 f32
  float* zs2 = zs1 + (size_t)N * 32;             // N*32 f32
  float* hbuf = zs2 + (size_t)N * 32;            // N*32 f32
  unsigned short* zn1 = (unsigned short*)(hbuf + (size_t)N * 32);  // N*32
  unsigned short* zn2 = zn1 + (size_t)N * 32;    // N*32 bf16
  int* ebuf = (int*)(zn2 + (size_t)N * 32);      // E
  int* blkhist = ebuf + E;                       // NBUK*G
  int* bb = blkhist + (size_t)NBUK * G;          // NBUK+1
  int* totals = bb + NBUK + 1;                   // NBUK
  int* bar = (int*)(((size_t)(totals + NBUK) + 63) & ~(size_t)63);  // 16 ints

  hipMemsetAsync(bar, 0, 64, stream);

  const int* srcp = ei;
  const int* dstp = ei + E;

  k_all<<<G, 256, 0, stream>>>(x, srcp, dstp, W1l, b1, W1r, W2l, b2, W2r, out,
                               zs1, zs2, hbuf, zn1, zn2, ebuf, blkhist, bb,
                               totals, bar, N, E, chunk);
}